// Round 2
// baseline (418.992 us; speedup 1.0000x reference)
//
#include <hip/hip_runtime.h>
#include <math.h>

#define OBS_DIM 115
#define N_AGENTS 11
#define ROWS 32          // rows staged per block
#define SROW 385         // LDS row stride in floats; 385 % 32 == 1 -> conflict-free
#define TELEM 377        // 11*33 agent data + 3 extras (bx,by,team) + 11 q
// per-row LDS layout:
//   [a*33 + 0..21]  : agent a cols 0..21   (candidate positions)
//   [a*33 + 22..32] : agent a cols 97..107 (ID one-hot block)
//   [363,364,365]   : gs cols 88, 89, 95   (ball x, ball y, team flag)
//   [366..376]      : q[row, 0..10]

__global__ __launch_bounds__(256) void qmix_kernel(
    const float* __restrict__ q,    // [B, 11]
    const float* __restrict__ gs,   // [B, 1265]
    float* __restrict__ out,        // [B]
    int B)
{
    __shared__ float sm[ROWS * SROW];

    const int tid  = threadIdx.x;
    const int wave = tid >> 6;      // 0..3
    const int lane = tid & 63;
    const int row0 = blockIdx.x * ROWS;

    // ---- hoisted column map: o = it*64 + lane -> source column ----
    int cols[6];
    #pragma unroll
    for (int it = 0; it < 6; ++it) {
        int o = it * 64 + lane;
        int col;
        if (o < 363) {
            int a = o / 33;
            int j = o - a * 33;
            col = a * OBS_DIM + (j < 22 ? j : j + 75);   // j>=22 -> 97+(j-22)
        } else if (o == 363) col = 88;
        else if (o == 364) col = 89;
        else                col = 95;                    // o==365 (unused for o>=366)
        cols[it] = col;
    }

    // ---- cooperative staging: each wave loads 8 rows, coalesced within rows ----
    #pragma unroll
    for (int rr = 0; rr < 8; ++rr) {
        int r = wave * 8 + rr;
        int rg = row0 + r;
        if (rg < B) {
            long gbase = (long)rg * (N_AGENTS * OBS_DIM);
            long qbase = (long)rg * N_AGENTS;
            #pragma unroll
            for (int it = 0; it < 6; ++it) {
                int o = it * 64 + lane;
                if (o < 366) {
                    sm[r * SROW + o] = gs[gbase + cols[it]];
                } else if (o < TELEM) {
                    sm[r * SROW + o] = q[qbase + (o - 366)];
                }
            }
        }
    }
    __syncthreads();

    // ---- compute: one thread per row (threads 0..31) ----
    if (tid < ROWS && row0 + tid < B) {
        const float* s = &sm[tid * SROW];

        float bx = s[363];
        float by = s[364];
        float team = s[365];
        float gx0 = bx - 1.0f;
        float ball_goal_dist = sqrtf(gx0 * gx0 + by * by);
        bool valid = (team != 0.0f) && (ball_goal_dist > 0.19f) && (ball_goal_dist < 0.99f);

        float dist[N_AGENTS];
        float gd[N_AGENTS];

        #pragma unroll
        for (int a = 0; a < N_AGENTS; ++a) {
            const float* base = s + a * 33;
            // argmax over ID block, first-max tie-break (strict >)
            float best = base[22];
            int bi = 0;
            #pragma unroll
            for (int j = 1; j < 11; ++j) {
                float v = base[22 + j];
                if (v > best) { best = v; bi = j; }
            }
            float px = base[2 * bi];
            float py = base[2 * bi + 1];
            float ddx = px - bx;
            float ddy = py - by;
            dist[a] = sqrtf(ddx * ddx + ddy * ddy);
            float ggx = px - 1.0f;
            gd[a] = sqrtf(ggx * ggx + py * py);
        }

        // argmin, first-min tie-break (strict <)
        int holder = 0;
        float dmin = dist[0];
        #pragma unroll
        for (int a = 1; a < N_AGENTS; ++a) {
            if (dist[a] < dmin) { dmin = dist[a]; holder = a; }
        }

        float comb[N_AGENTS];
        float m = -INFINITY;
        #pragma unroll
        for (int a = 0; a < N_AGENTS; ++a) {
            float c;
            if (valid) {
                c = (a == holder) ? 5.0f : 0.0f;
            } else {
                c = 1.0f / (gd[a] + 1e-6f);
            }
            comb[a] = c;
            m = fmaxf(m, c);
        }

        float ssum = 0.0f;
        float acc = 0.0f;
        #pragma unroll
        for (int a = 0; a < N_AGENTS; ++a) {
            float w = expf(comb[a] - m);
            ssum += w;
            acc += s[366 + a] * w;
        }

        out[row0 + tid] = acc * (float)N_AGENTS / ssum;
    }
}

extern "C" void kernel_launch(void* const* d_in, const int* in_sizes, int n_in,
                              void* d_out, int out_size, void* d_ws, size_t ws_size,
                              hipStream_t stream) {
    const float* q  = (const float*)d_in[0];   // agents_q  [128,512,11]
    const float* gs = (const float*)d_in[1];   // global_state [128,512,1265]
    float* out = (float*)d_out;                // [128,512,1] f32

    int B = in_sizes[0] / N_AGENTS;            // 65536
    int grid = (B + ROWS - 1) / ROWS;          // 2048
    qmix_kernel<<<grid, 256, 0, stream>>>(q, gs, out, B);
}